// Round 4
// baseline (374.324 us; speedup 1.0000x reference)
//
#include <hip/hip_runtime.h>
#include <hip/hip_fp16.h>

#define S_TOK 8192
#define DDIM  1024
#define HDIM  4096
#define NEXP  8
#define CAP   1024

typedef __attribute__((ext_vector_type(8))) _Float16 half8;
typedef __attribute__((ext_vector_type(4))) float f32x4;

__device__ __forceinline__ void load_lds16(const _Float16* g, _Float16* l) {
  __builtin_amdgcn_global_load_lds(
      (const __attribute__((address_space(1))) unsigned int*)g,
      (__attribute__((address_space(3))) unsigned int*)l, 16, 0, 0);
}

// ---------------- gating: logits = x @ wg, softmax, top-1 ----------------
__global__ __launch_bounds__(256) void moe_gating(const float* __restrict__ x,
                                                  const float* __restrict__ wg,
                                                  int* __restrict__ eidx,
                                                  float* __restrict__ gtok) {
  const int s = blockIdx.x * 4 + (threadIdx.x >> 6);
  const int lane = threadIdx.x & 63;
  const float* xr = x + (size_t)s * DDIM;
  float acc[NEXP];
#pragma unroll
  for (int e = 0; e < NEXP; ++e) acc[e] = 0.f;
  for (int d = lane; d < DDIM; d += 64) {
    float xv = xr[d];
    const float4* wrow = (const float4*)(wg + (size_t)d * NEXP);
    float4 w0 = wrow[0], w1v = wrow[1];
    acc[0] += xv * w0.x;  acc[1] += xv * w0.y;
    acc[2] += xv * w0.z;  acc[3] += xv * w0.w;
    acc[4] += xv * w1v.x; acc[5] += xv * w1v.y;
    acc[6] += xv * w1v.z; acc[7] += xv * w1v.w;
  }
#pragma unroll
  for (int off = 32; off > 0; off >>= 1) {
#pragma unroll
    for (int e = 0; e < NEXP; ++e) acc[e] += __shfl_down(acc[e], off);
  }
  if (lane == 0) {
    int best = 0; float bv = acc[0];
#pragma unroll
    for (int e = 1; e < NEXP; ++e) if (acc[e] > bv) { bv = acc[e]; best = e; }
    float sum = 0.f;
#pragma unroll
    for (int e = 0; e < NEXP; ++e) sum += expf(acc[e] - bv);
    eidx[s] = best;
    gtok[s] = 1.f / sum;   // exp(best - max) == 1
  }
}

// ---------------- ordered slot assignment (cumsum semantics) ----------------
__global__ __launch_bounds__(512) void moe_scan(const int* __restrict__ eidx,
                                                const float* __restrict__ gtok,
                                                int* __restrict__ s2t,
                                                float* __restrict__ rgate) {
  const int tid = threadIdx.x;
  for (int i = tid; i < NEXP * CAP; i += 512) { s2t[i] = -1; rgate[i] = 0.f; }
  __syncthreads();
  const int w = tid >> 6, lane = tid & 63;
  const unsigned long long below = (1ull << lane) - 1ull;
  int count = 0;
  int e_next = eidx[lane];
  float g_next = gtok[lane];
  for (int base = 0; base < S_TOK; base += 64) {
    int e = e_next; float g = g_next;
    if (base + 64 < S_TOK) { e_next = eidx[base + 64 + lane]; g_next = gtok[base + 64 + lane]; }
    unsigned long long mask = __ballot(e == w);
    if (e == w) {
      int slot = count + __popcll(mask & below);
      if (slot < CAP) { s2t[w * CAP + slot] = base + lane; rgate[w * CAP + slot] = g; }
    }
    count += __popcll(mask);
  }
}

// ---------------- dispatch: gather kept tokens, fp32 -> fp16 ----------------
__global__ __launch_bounds__(128) void moe_dispatch(const float* __restrict__ x,
                                                    const int* __restrict__ s2t,
                                                    _Float16* __restrict__ disp) {
  const int row = blockIdx.x;
  const int t = threadIdx.x;
  const int token = s2t[row];
  half8 v;
  if (token >= 0) {
    const float4* xr = (const float4*)(x + (size_t)token * DDIM);
    float4 a = xr[2 * t], b = xr[2 * t + 1];
    v[0] = (_Float16)a.x; v[1] = (_Float16)a.y; v[2] = (_Float16)a.z; v[3] = (_Float16)a.w;
    v[4] = (_Float16)b.x; v[5] = (_Float16)b.y; v[6] = (_Float16)b.z; v[7] = (_Float16)b.w;
  } else {
#pragma unroll
    for (int i = 0; i < 8; ++i) v[i] = (_Float16)0.f;
  }
  *(half8*)(disp + (size_t)row * DDIM + t * 8) = v;
}

// ---------------- transpose + fp32->fp16 convert: in[R][Cc] -> out[Cc][R] ----------------
__global__ __launch_bounds__(256) void transpose_cvt(const float* __restrict__ in,
                                                     _Float16* __restrict__ out,
                                                     int R, int Cc) {
  __shared__ float tile[64][65];
  const size_t mat = (size_t)R * Cc;
  const float* ip = in + (size_t)blockIdx.z * mat;
  _Float16* op = out + (size_t)blockIdx.z * mat;
  const int r0 = blockIdx.y * 64, c0 = blockIdx.x * 64;
  const int tx = threadIdx.x & 63, ty = threadIdx.x >> 6;
#pragma unroll
  for (int i = 0; i < 16; ++i) {
    int rl = ty * 16 + i;
    tile[rl][tx] = ip[(size_t)(r0 + rl) * Cc + c0 + tx];
  }
  __syncthreads();
  const int cl = threadIdx.x >> 3;        // 0..31
  const int rch = (threadIdx.x & 7) * 8;  // row chunk base
#pragma unroll
  for (int pass = 0; pass < 2; ++pass) {
    int cc = cl + pass * 32;
    half8 v;
#pragma unroll
    for (int i = 0; i < 8; ++i) v[i] = (_Float16)tile[rch + i][cc];
    *(half8*)(op + (size_t)(c0 + cc) * R + r0 + rch) = v;
  }
}

// ---------------- grouped GEMM, counted-vmcnt pipelined (T3+T4) ----------------
// C[M=1024 per expert][N = NX*128] = A[z][M][K] @ B[z][N][K]^T, fp16 in, fp32 acc.
// BM=256, BN=128, BK=64. 512 threads = 8 waves (2M x 4N), wave tile 128x32.
// LDS: A 2buf x 256x64, B 2buf x 128x64 (fp16) = 96 KB -> 1 block/CU.
// Per K-tile: burst 6 global_load_lds for kt+1 (buffer freed at the immediately
// preceding barrier), s_waitcnt vmcnt(6) (never 0 in steady state), raw
// s_barrier, then 2 phases {10 ds_read_b128 + 16 MFMA} with setprio.
// K-chunk XOR swizzle (chunk ^= row&7) applied on BOTH the global source of
// global_load_lds (LDS dest linear) and the ds_read address (rule #21).
template <int KDIM, int NX, bool FIRST>
__global__ __launch_bounds__(512, 2) void ffn_gemm8(const _Float16* __restrict__ A_set,
                                                    const _Float16* __restrict__ B_set,
                                                    _Float16* __restrict__ Hout,
                                                    float* __restrict__ Y,
                                                    const int* __restrict__ s2t,
                                                    const float* __restrict__ rgate) {
  __shared__ __align__(16) _Float16 As[2 * 16384];  // [buf][256][64]
  __shared__ __align__(16) _Float16 Bs[2 * 8192];   // [buf][128][64]
  constexpr int NT = KDIM / 64;       // K-tiles (even)
  constexpr int PER_E = 4 * NX;       // 4 m-tiles x NX n-tiles per expert
  const int wg = blockIdx.x;
  const int swz = (wg & 7) * PER_E + (wg >> 3);  // bijective: xcd == expert
  const int z = swz / PER_E;
  const int s2 = swz % PER_E;
  const int mp = s2 / (2 * NX);                  // m-pair
  const int inner = s2 % (2 * NX);
  const int m0 = (mp * 2 + (inner & 1)) * 256;
  const int n0 = (inner >> 1) * 128;

  const int tid = threadIdx.x;
  const int trow = tid >> 3;                     // 0..63 staging row
  const int schunk = ((tid & 7) ^ (trow & 7)) * 8;  // pre-swizzled source k-offset

  const _Float16* Ae = A_set + (size_t)z * 1024 * KDIM;
  const _Float16* Be = B_set + (size_t)z * (size_t)(NX * 128) * KDIM;

  const int lane = tid & 63;
  const int wid = tid >> 6;
  const int wr = wid >> 2, wc = wid & 3;
  const int fr = lane & 15, fq = lane >> 4;

  f32x4 acc[8][2];
#pragma unroll
  for (int m = 0; m < 8; ++m)
#pragma unroll
    for (int n = 0; n < 2; ++n) acc[m][n] = {0.f, 0.f, 0.f, 0.f};

  auto BURST = [&](int kt) {   // 6 global_load_lds: one K-tile (A 4, B 2)
    const int buf = kt & 1;
    const size_t kb = (size_t)kt * 64 + schunk;
#pragma unroll
    for (int j = 0; j < 4; ++j)
      load_lds16(Ae + (size_t)(m0 + j * 64 + trow) * KDIM + kb,
                 As + buf * 16384 + j * 4096 + tid * 8);
#pragma unroll
    for (int j = 0; j < 2; ++j)
      load_lds16(Be + (size_t)(n0 + j * 64 + trow) * KDIM + kb,
                 Bs + buf * 8192 + j * 4096 + tid * 8);
  };

  auto PHASE = [&](int buf, int ks) {
    const _Float16* Ab = As + buf * 16384;
    const _Float16* Bb = Bs + buf * 8192;
    half8 af[8], bf[2];
#pragma unroll
    for (int m = 0; m < 8; ++m) {
      int r = wr * 128 + m * 16 + fr;
      af[m] = *(const half8*)(Ab + r * 64 + (((ks * 4 + fq) ^ (r & 7)) << 3));
    }
#pragma unroll
    for (int n = 0; n < 2; ++n) {
      int r = wc * 32 + n * 16 + fr;
      bf[n] = *(const half8*)(Bb + r * 64 + (((ks * 4 + fq) ^ (r & 7)) << 3));
    }
    __builtin_amdgcn_s_setprio(1);
#pragma unroll
    for (int m = 0; m < 8; ++m)
#pragma unroll
      for (int n = 0; n < 2; ++n)
        acc[m][n] = __builtin_amdgcn_mfma_f32_16x16x32_f16(af[m], bf[n], acc[m][n], 0, 0, 0);
    __builtin_amdgcn_s_setprio(0);
  };

#define SFENCE __builtin_amdgcn_sched_barrier(0)
#define BAR    __builtin_amdgcn_s_barrier()

  BURST(0);                      // prologue: K-tile 0 in flight
#pragma unroll 1
  for (int kt = 0; kt < NT; kt += 2) {
    // ---- K-tile kt (buf kt&1): buffer for kt+1 was freed at prev closing barrier
    BURST(kt + 1);               // kt+1 <= NT-1 always (NT even)
    asm volatile("s_waitcnt vmcnt(6)" ::: "memory");  // kt's 6 loads landed
    SFENCE; BAR; SFENCE;
    PHASE(kt & 1, 0);
    SFENCE; BAR; SFENCE;
    PHASE(kt & 1, 1);
    SFENCE; BAR; SFENCE;         // frees buf kt&1
    // ---- K-tile kt+1 (buf ^1)
    if (kt + 2 < NT) {
      BURST(kt + 2);
      asm volatile("s_waitcnt vmcnt(6)" ::: "memory");
    } else {
      asm volatile("s_waitcnt vmcnt(0)" ::: "memory");  // epilogue drain
    }
    SFENCE; BAR; SFENCE;
    PHASE((kt + 1) & 1, 0);
    SFENCE; BAR; SFENCE;
    PHASE((kt + 1) & 1, 1);
    SFENCE; BAR; SFENCE;
  }
#undef SFENCE
#undef BAR

  const int rb = wr * 128 + fq * 4;       // + m*16 + j
  const int cb = n0 + wc * 32 + fr;       // + n*16
  if (FIRST) {
#pragma unroll
    for (int m = 0; m < 8; ++m) {
#pragma unroll
      for (int j = 0; j < 4; ++j) {
        size_t row = (size_t)z * 1024 + m0 + rb + m * 16 + j;
#pragma unroll
        for (int n = 0; n < 2; ++n)
          Hout[row * (size_t)(NX * 128) + cb + n * 16] = (_Float16)fmaxf(acc[m][n][j], 0.f);
      }
    }
  } else {
#pragma unroll
    for (int m = 0; m < 8; ++m) {
      int srow = z * CAP + m0 + rb + m * 16;
#pragma unroll
      for (int j = 0; j < 4; ++j) {
        int token = s2t[srow + j];
        if (token < 0) continue;
        float g = rgate[srow + j];
#pragma unroll
        for (int n = 0; n < 2; ++n)
          Y[(size_t)token * DDIM + cb + n * 16] = acc[m][n][j] * g;
      }
    }
  }
}

extern "C" void kernel_launch(void* const* d_in, const int* in_sizes, int n_in,
                              void* d_out, int out_size, void* d_ws, size_t ws_size,
                              hipStream_t stream) {
  const float* x  = (const float*)d_in[0];
  const float* wg = (const float*)d_in[1];
  const float* w1 = (const float*)d_in[2];
  const float* w2 = (const float*)d_in[3];
  float* y = (float*)d_out;

  char* ws = (char*)d_ws;
  int*   eidx  = (int*)(ws);
  float* gtok  = (float*)(ws + 32768);
  int*   s2t   = (int*)(ws + 65536);
  float* rgate = (float*)(ws + 98304);
  _Float16* disp = (_Float16*)(ws + 131072);
  char* big = ws + 131072 + (size_t)NEXP * CAP * DDIM * 2;  // after disp (16 MB)
  _Float16* hbuf = (_Float16*)big;                  // [E][C][H] fp16, 67 MB
  _Float16* wt   = (_Float16*)(big + 67108864);     // shared w1t then w2t, 67 MB

  moe_gating<<<S_TOK / 4, 256, 0, stream>>>(x, wg, eidx, gtok);
  moe_scan<<<1, 512, 0, stream>>>(eidx, gtok, s2t, rgate);
  moe_dispatch<<<NEXP * CAP, 128, 0, stream>>>(x, s2t, disp);
  (void)hipMemsetAsync(d_out, 0, (size_t)out_size * sizeof(float), stream);

  // GEMM1: [C,1024] x [1024,4096] -> relu -> hbuf fp16.  grid 8e x 4m x 32n = 1024
  transpose_cvt<<<dim3(HDIM / 64, DDIM / 64, NEXP), 256, 0, stream>>>(w1, wt, DDIM, HDIM);
  ffn_gemm8<DDIM, 32, true><<<1024, 512, 0, stream>>>(
      disp, wt, hbuf, nullptr, nullptr, nullptr);

  // GEMM2: [C,4096] x [4096,1024] -> scatter to y.  grid 8e x 4m x 8n = 256
  transpose_cvt<<<dim3(DDIM / 64, HDIM / 64, NEXP), 256, 0, stream>>>(w2, wt, HDIM, DDIM);
  ffn_gemm8<HDIM, 8, false><<<256, 512, 0, stream>>>(
      hbuf, wt, nullptr, y, s2t, rgate);
}

// Round 5
// 365.621 us; speedup vs baseline: 1.0238x; 1.0238x over previous
//
#include <hip/hip_runtime.h>
#include <hip/hip_fp16.h>

#define S_TOK 8192
#define DDIM  1024
#define HDIM  4096
#define NEXP  8
#define CAP   1024

typedef __attribute__((ext_vector_type(8))) _Float16 half8;
typedef __attribute__((ext_vector_type(4))) float f32x4;

__device__ __forceinline__ void load_lds16(const _Float16* g, _Float16* l) {
  __builtin_amdgcn_global_load_lds(
      (const __attribute__((address_space(1))) unsigned int*)g,
      (__attribute__((address_space(3))) unsigned int*)l, 16, 0, 0);
}

// ---------------- gating: logits = x @ wg, softmax, top-1 ----------------
__global__ __launch_bounds__(256) void moe_gating(const float* __restrict__ x,
                                                  const float* __restrict__ wg,
                                                  int* __restrict__ eidx,
                                                  float* __restrict__ gtok) {
  const int s = blockIdx.x * 4 + (threadIdx.x >> 6);
  const int lane = threadIdx.x & 63;
  const float* xr = x + (size_t)s * DDIM;
  float acc[NEXP];
#pragma unroll
  for (int e = 0; e < NEXP; ++e) acc[e] = 0.f;
  for (int d = lane; d < DDIM; d += 64) {
    float xv = xr[d];
    const float4* wrow = (const float4*)(wg + (size_t)d * NEXP);
    float4 w0 = wrow[0], w1v = wrow[1];
    acc[0] += xv * w0.x;  acc[1] += xv * w0.y;
    acc[2] += xv * w0.z;  acc[3] += xv * w0.w;
    acc[4] += xv * w1v.x; acc[5] += xv * w1v.y;
    acc[6] += xv * w1v.z; acc[7] += xv * w1v.w;
  }
#pragma unroll
  for (int off = 32; off > 0; off >>= 1) {
#pragma unroll
    for (int e = 0; e < NEXP; ++e) acc[e] += __shfl_down(acc[e], off);
  }
  if (lane == 0) {
    int best = 0; float bv = acc[0];
#pragma unroll
    for (int e = 1; e < NEXP; ++e) if (acc[e] > bv) { bv = acc[e]; best = e; }
    float sum = 0.f;
#pragma unroll
    for (int e = 0; e < NEXP; ++e) sum += expf(acc[e] - bv);
    eidx[s] = best;
    gtok[s] = 1.f / sum;   // exp(best - max) == 1
  }
}

// ---------------- ordered slot assignment (cumsum semantics) ----------------
__global__ __launch_bounds__(512) void moe_scan(const int* __restrict__ eidx,
                                                const float* __restrict__ gtok,
                                                int* __restrict__ s2t,
                                                float* __restrict__ rgate) {
  const int tid = threadIdx.x;
  for (int i = tid; i < NEXP * CAP; i += 512) { s2t[i] = -1; rgate[i] = 0.f; }
  __syncthreads();
  const int w = tid >> 6, lane = tid & 63;
  const unsigned long long below = (1ull << lane) - 1ull;
  int count = 0;
  int e_next = eidx[lane];
  float g_next = gtok[lane];
  for (int base = 0; base < S_TOK; base += 64) {
    int e = e_next; float g = g_next;
    if (base + 64 < S_TOK) { e_next = eidx[base + 64 + lane]; g_next = gtok[base + 64 + lane]; }
    unsigned long long mask = __ballot(e == w);
    if (e == w) {
      int slot = count + __popcll(mask & below);
      if (slot < CAP) { s2t[w * CAP + slot] = base + lane; rgate[w * CAP + slot] = g; }
    }
    count += __popcll(mask);
  }
}

// ---------------- dispatch: gather kept tokens, fp32 -> fp16 ----------------
__global__ __launch_bounds__(128) void moe_dispatch(const float* __restrict__ x,
                                                    const int* __restrict__ s2t,
                                                    _Float16* __restrict__ disp) {
  const int row = blockIdx.x;
  const int t = threadIdx.x;
  const int token = s2t[row];
  half8 v;
  if (token >= 0) {
    const float4* xr = (const float4*)(x + (size_t)token * DDIM);
    float4 a = xr[2 * t], b = xr[2 * t + 1];
    v[0] = (_Float16)a.x; v[1] = (_Float16)a.y; v[2] = (_Float16)a.z; v[3] = (_Float16)a.w;
    v[4] = (_Float16)b.x; v[5] = (_Float16)b.y; v[6] = (_Float16)b.z; v[7] = (_Float16)b.w;
  } else {
#pragma unroll
    for (int i = 0; i < 8; ++i) v[i] = (_Float16)0.f;
  }
  *(half8*)(disp + (size_t)row * DDIM + t * 8) = v;
}

// ---------------- transpose + fp32->fp16 convert: in[R][Cc] -> out[Cc][R] ----------------
__global__ __launch_bounds__(256) void transpose_cvt(const float* __restrict__ in,
                                                     _Float16* __restrict__ out,
                                                     int R, int Cc) {
  __shared__ float tile[64][65];
  const size_t mat = (size_t)R * Cc;
  const float* ip = in + (size_t)blockIdx.z * mat;
  _Float16* op = out + (size_t)blockIdx.z * mat;
  const int r0 = blockIdx.y * 64, c0 = blockIdx.x * 64;
  const int tx = threadIdx.x & 63, ty = threadIdx.x >> 6;
#pragma unroll
  for (int i = 0; i < 16; ++i) {
    int rl = ty * 16 + i;
    tile[rl][tx] = ip[(size_t)(r0 + rl) * Cc + c0 + tx];
  }
  __syncthreads();
  const int cl = threadIdx.x >> 3;        // 0..31
  const int rch = (threadIdx.x & 7) * 8;  // row chunk base
#pragma unroll
  for (int pass = 0; pass < 2; ++pass) {
    int cc = cl + pass * 32;
    half8 v;
#pragma unroll
    for (int i = 0; i < 8; ++i) v[i] = (_Float16)tile[rch + i][cc];
    *(half8*)(op + (size_t)(c0 + cc) * R + r0 + rch) = v;
  }
}

// ---------------- grouped GEMM, m201-style phased schedule ----------------
// C[1024 x NX*128 per expert] = A[z] @ B[z]^T (B stored [N][K]). fp16 in, fp32 acc.
// BM=256, BN=128, BK=64. 512 threads = 8 waves as 4M x 2N (wave tile 64x64).
// LDS: 3 K-tile buffers (A 32KB + B 16KB each) = 144 KB -> 1 block/CU.
// Per K-tile, 4 phases (kh,mh). Each phase: ds_read fragments BEFORE barrier
// (overlaps other waves' MFMA), then barrier -> setprio(1) -> 8 MFMA -> barrier.
// BURST(kt+2) issued at kt-phase0 (its buffer was freed at kt-1 phase3 barrier);
// vmcnt(6) once per K-tile at phase3 drains tile kt+1's 6 loads (12 in flight).
// XOR swizzle (k-chunk ^= row&7) on BOTH staging source and ds_read (rule #21).
template <int KDIM, int NX, bool FIRST>
__global__ __launch_bounds__(512, 2) void ffn_gemm3(const _Float16* __restrict__ A_set,
                                                    const _Float16* __restrict__ B_set,
                                                    _Float16* __restrict__ Hout,
                                                    float* __restrict__ Y,
                                                    const int* __restrict__ s2t,
                                                    const float* __restrict__ rgate) {
  __shared__ __align__(16) _Float16 As[3 * 16384];  // 3 x [256][64]
  __shared__ __align__(16) _Float16 Bs[3 * 8192];   // 3 x [128][64]
  constexpr int NT = KDIM / 64;
  constexpr int PER_E = 4 * NX;
  const int wg = blockIdx.x;
  const int swz = (wg & 7) * PER_E + (wg >> 3);   // bijective; xcd-chunked
  const int z = swz / PER_E;                      // expert
  const int s2 = swz % PER_E;
  const int m0 = (s2 & 3) * 256;
  const int n0 = (s2 >> 2) * 128;

  const int tid = threadIdx.x;
  const int trow = tid >> 3;                          // 0..63 staging row
  const int schunk = ((tid & 7) ^ (trow & 7)) * 8;    // pre-swizzled src k-offset

  const _Float16* Ae = A_set + (size_t)z * 1024 * KDIM;
  const _Float16* Be = B_set + (size_t)z * (size_t)(NX * 128) * KDIM;

  const int lane = tid & 63;
  const int wid = tid >> 6;
  const int wr = wid >> 1, wc = wid & 1;              // 4M x 2N wave grid
  const int fr = lane & 15, fq = lane >> 4;
  const int arow = wr * 64 + fr;                      // + m*16
  const int brow = wc * 64 + fr;                      // + n*16

  f32x4 acc[4][4];
#pragma unroll
  for (int m = 0; m < 4; ++m)
#pragma unroll
    for (int n = 0; n < 4; ++n) acc[m][n] = {0.f, 0.f, 0.f, 0.f};

  auto BURST = [&](int kt) {   // 6 global_load_lds for K-tile kt into buf kt%3
    const int buf = kt % 3;
    const size_t kb = (size_t)kt * 64 + schunk;
#pragma unroll
    for (int j = 0; j < 4; ++j)
      load_lds16(Ae + (size_t)(m0 + j * 64 + trow) * KDIM + kb,
                 As + buf * 16384 + j * 4096 + tid * 8);
#pragma unroll
    for (int j = 0; j < 2; ++j)
      load_lds16(Be + (size_t)(n0 + j * 64 + trow) * KDIM + kb,
                 Bs + buf * 8192 + j * 4096 + tid * 8);
  };

#define SFENCE __builtin_amdgcn_sched_barrier(0)
#define BARRIER __builtin_amdgcn_s_barrier()

  // PHASE(MH, KH, LOADB, PRE): ds_read frags (pre-barrier), PRE, barrier,
  // 8 MFMA (m = MH*2, MH*2+1), barrier.
#define PHASE(MH, KH, LOADB, ...)                                              \
  {                                                                            \
    half8 af0, af1;                                                            \
    {                                                                          \
      int r0_ = arow + (MH * 2) * 16;                                          \
      int r1_ = r0_ + 16;                                                      \
      af0 = *(const half8*)(Ab + r0_ * 64 + ((((KH)*4 + fq) ^ (r0_ & 7)) << 3)); \
      af1 = *(const half8*)(Ab + r1_ * 64 + ((((KH)*4 + fq) ^ (r1_ & 7)) << 3)); \
    }                                                                          \
    if (LOADB) {                                                               \
      _Pragma("unroll")                                                        \
      for (int n = 0; n < 4; ++n) {                                            \
        int rb_ = brow + n * 16;                                               \
        bf[n] = *(const half8*)(Bb + rb_ * 64 + ((((KH)*4 + fq) ^ (rb_ & 7)) << 3)); \
      }                                                                        \
    }                                                                          \
    __VA_ARGS__;                                                               \
    SFENCE; BARRIER; SFENCE;                                                   \
    __builtin_amdgcn_s_setprio(1);                                             \
    acc[MH * 2][0] = __builtin_amdgcn_mfma_f32_16x16x32_f16(af0, bf[0], acc[MH * 2][0], 0, 0, 0); \
    acc[MH * 2 + 1][0] = __builtin_amdgcn_mfma_f32_16x16x32_f16(af1, bf[0], acc[MH * 2 + 1][0], 0, 0, 0); \
    acc[MH * 2][1] = __builtin_amdgcn_mfma_f32_16x16x32_f16(af0, bf[1], acc[MH * 2][1], 0, 0, 0); \
    acc[MH * 2 + 1][1] = __builtin_amdgcn_mfma_f32_16x16x32_f16(af1, bf[1], acc[MH * 2 + 1][1], 0, 0, 0); \
    acc[MH * 2][2] = __builtin_amdgcn_mfma_f32_16x16x32_f16(af0, bf[2], acc[MH * 2][2], 0, 0, 0); \
    acc[MH * 2 + 1][2] = __builtin_amdgcn_mfma_f32_16x16x32_f16(af1, bf[2], acc[MH * 2 + 1][2], 0, 0, 0); \
    acc[MH * 2][3] = __builtin_amdgcn_mfma_f32_16x16x32_f16(af0, bf[3], acc[MH * 2][3], 0, 0, 0); \
    acc[MH * 2 + 1][3] = __builtin_amdgcn_mfma_f32_16x16x32_f16(af1, bf[3], acc[MH * 2 + 1][3], 0, 0, 0); \
    __builtin_amdgcn_s_setprio(0);                                             \
    SFENCE; BARRIER;                                                           \
  }

  // prologue: tiles 0 and 1 in flight; wait tile 0 (12 -> 6 outstanding)
  BURST(0);
  BURST(1);
  asm volatile("s_waitcnt vmcnt(6)" ::: "memory");
  BARRIER;

#pragma unroll 1
  for (int kt = 0; kt < NT; ++kt) {
    const _Float16* Ab = As + (kt % 3) * 16384;
    const _Float16* Bb = Bs + (kt % 3) * 8192;
    half8 bf[4];
    PHASE(0, 0, true,  { if (kt + 2 < NT) BURST(kt + 2); });
    PHASE(1, 0, false, {});
    PHASE(0, 1, true,  {});
    PHASE(1, 1, false, {
      if (kt + 2 < NT) { asm volatile("s_waitcnt vmcnt(6)" ::: "memory"); }
      else             { asm volatile("s_waitcnt vmcnt(0)" ::: "memory"); }
    });
  }
#undef PHASE
#undef SFENCE
#undef BARRIER

  const int rb = wr * 64 + fq * 4;        // + m*16 + j
  const int cb = n0 + wc * 64 + fr;       // + n*16
  if (FIRST) {
#pragma unroll
    for (int m = 0; m < 4; ++m) {
#pragma unroll
      for (int j = 0; j < 4; ++j) {
        size_t row = (size_t)z * 1024 + m0 + rb + m * 16 + j;
#pragma unroll
        for (int n = 0; n < 4; ++n)
          Hout[row * (size_t)(NX * 128) + cb + n * 16] = (_Float16)fmaxf(acc[m][n][j], 0.f);
      }
    }
  } else {
#pragma unroll
    for (int m = 0; m < 4; ++m) {
      int srow = z * CAP + m0 + rb + m * 16;
#pragma unroll
      for (int j = 0; j < 4; ++j) {
        int token = s2t[srow + j];
        if (token < 0) continue;
        float g = rgate[srow + j];
#pragma unroll
        for (int n = 0; n < 4; ++n)
          Y[(size_t)token * DDIM + cb + n * 16] = acc[m][n][j] * g;
      }
    }
  }
}

extern "C" void kernel_launch(void* const* d_in, const int* in_sizes, int n_in,
                              void* d_out, int out_size, void* d_ws, size_t ws_size,
                              hipStream_t stream) {
  const float* x  = (const float*)d_in[0];
  const float* wg = (const float*)d_in[1];
  const float* w1 = (const float*)d_in[2];
  const float* w2 = (const float*)d_in[3];
  float* y = (float*)d_out;

  char* ws = (char*)d_ws;
  int*   eidx  = (int*)(ws);
  float* gtok  = (float*)(ws + 32768);
  int*   s2t   = (int*)(ws + 65536);
  float* rgate = (float*)(ws + 98304);
  _Float16* disp = (_Float16*)(ws + 131072);
  char* big = ws + 131072 + (size_t)NEXP * CAP * DDIM * 2;  // after disp (16 MB)
  _Float16* hbuf = (_Float16*)big;                  // [E][C][H] fp16, 67 MB
  _Float16* wt   = (_Float16*)(big + 67108864);     // shared w1t then w2t, 67 MB

  moe_gating<<<S_TOK / 4, 256, 0, stream>>>(x, wg, eidx, gtok);
  moe_scan<<<1, 512, 0, stream>>>(eidx, gtok, s2t, rgate);
  moe_dispatch<<<NEXP * CAP, 128, 0, stream>>>(x, s2t, disp);
  (void)hipMemsetAsync(d_out, 0, (size_t)out_size * sizeof(float), stream);

  // GEMM1: [C,1024] x [1024,4096] -> relu -> hbuf fp16.  grid 8e x 4m x 32n = 1024
  transpose_cvt<<<dim3(HDIM / 64, DDIM / 64, NEXP), 256, 0, stream>>>(w1, wt, DDIM, HDIM);
  ffn_gemm3<DDIM, 32, true><<<1024, 512, 0, stream>>>(
      disp, wt, hbuf, nullptr, nullptr, nullptr);

  // GEMM2: [C,4096] x [4096,1024] -> scatter to y.  grid 8e x 4m x 8n = 256
  transpose_cvt<<<dim3(DDIM / 64, HDIM / 64, NEXP), 256, 0, stream>>>(w2, wt, HDIM, DDIM);
  ffn_gemm3<HDIM, 8, false><<<256, 512, 0, stream>>>(
      hbuf, wt, nullptr, y, s2t, rgate);
}

// Round 6
// 347.490 us; speedup vs baseline: 1.0772x; 1.0522x over previous
//
#include <hip/hip_runtime.h>
#include <hip/hip_fp16.h>

#define S_TOK 8192
#define DDIM  1024
#define HDIM  4096
#define NEXP  8
#define CAP   1024

typedef __attribute__((ext_vector_type(8))) _Float16 half8;
typedef __attribute__((ext_vector_type(4))) float f32x4;

__device__ __forceinline__ void load_lds16(const _Float16* g, _Float16* l) {
  __builtin_amdgcn_global_load_lds(
      (const __attribute__((address_space(1))) unsigned int*)g,
      (__attribute__((address_space(3))) unsigned int*)l, 16, 0, 0);
}

// ---------------- gating: logits = x @ wg, softmax, top-1 ----------------
__global__ __launch_bounds__(256) void moe_gating(const float* __restrict__ x,
                                                  const float* __restrict__ wg,
                                                  int* __restrict__ eidx,
                                                  float* __restrict__ gtok) {
  const int s = blockIdx.x * 4 + (threadIdx.x >> 6);
  const int lane = threadIdx.x & 63;
  const float* xr = x + (size_t)s * DDIM;
  float acc[NEXP];
#pragma unroll
  for (int e = 0; e < NEXP; ++e) acc[e] = 0.f;
  for (int d = lane; d < DDIM; d += 64) {
    float xv = xr[d];
    const float4* wrow = (const float4*)(wg + (size_t)d * NEXP);
    float4 w0 = wrow[0], w1v = wrow[1];
    acc[0] += xv * w0.x;  acc[1] += xv * w0.y;
    acc[2] += xv * w0.z;  acc[3] += xv * w0.w;
    acc[4] += xv * w1v.x; acc[5] += xv * w1v.y;
    acc[6] += xv * w1v.z; acc[7] += xv * w1v.w;
  }
#pragma unroll
  for (int off = 32; off > 0; off >>= 1) {
#pragma unroll
    for (int e = 0; e < NEXP; ++e) acc[e] += __shfl_down(acc[e], off);
  }
  if (lane == 0) {
    int best = 0; float bv = acc[0];
#pragma unroll
    for (int e = 1; e < NEXP; ++e) if (acc[e] > bv) { bv = acc[e]; best = e; }
    float sum = 0.f;
#pragma unroll
    for (int e = 0; e < NEXP; ++e) sum += expf(acc[e] - bv);
    eidx[s] = best;
    gtok[s] = 1.f / sum;   // exp(best - max) == 1
  }
}

// ---------------- hierarchical ordered slot assignment ----------------
__global__ __launch_bounds__(64) void scanA(const int* __restrict__ eidx,
                                            int* __restrict__ cnt) {
  const int blk = blockIdx.x;        // 128 blocks x 64 tokens
  const int lane = threadIdx.x;
  int e = eidx[blk * 64 + lane];
#pragma unroll
  for (int w = 0; w < NEXP; ++w) {
    unsigned long long m = __ballot(e == w);
    if (lane == 0) cnt[blk * NEXP + w] = __popcll(m);
  }
}

__global__ __launch_bounds__(64) void scanB(const int* __restrict__ cnt,
                                            int* __restrict__ off) {
  const int e = threadIdx.x;
  if (e < NEXP) {
    int run = 0;
    for (int b = 0; b < 128; ++b) { off[b * NEXP + e] = run; run += cnt[b * NEXP + e]; }
  }
}

__global__ __launch_bounds__(64) void scanC(const int* __restrict__ eidx,
                                            const float* __restrict__ gtok,
                                            const int* __restrict__ off,
                                            int* __restrict__ s2t,
                                            float* __restrict__ rgate) {
  const int blk = blockIdx.x;
  const int lane = threadIdx.x;
  const int tok = blk * 64 + lane;
  int e = eidx[tok];
  float g = gtok[tok];
  const unsigned long long below = (1ull << lane) - 1ull;
#pragma unroll
  for (int w = 0; w < NEXP; ++w) {
    unsigned long long m = __ballot(e == w);
    if (e == w) {
      int slot = off[blk * NEXP + w] + __popcll(m & below);
      if (slot < CAP) { s2t[w * CAP + slot] = tok; rgate[w * CAP + slot] = g; }
    }
  }
}

// ---------------- dispatch: gather kept tokens, fp32 -> fp16 ----------------
__global__ __launch_bounds__(128) void moe_dispatch(const float* __restrict__ x,
                                                    const int* __restrict__ s2t,
                                                    _Float16* __restrict__ disp) {
  const int row = blockIdx.x;
  const int t = threadIdx.x;
  const int token = s2t[row];
  half8 v;
  if (token >= 0) {
    const float4* xr = (const float4*)(x + (size_t)token * DDIM);
    float4 a = xr[2 * t], b = xr[2 * t + 1];
    v[0] = (_Float16)a.x; v[1] = (_Float16)a.y; v[2] = (_Float16)a.z; v[3] = (_Float16)a.w;
    v[4] = (_Float16)b.x; v[5] = (_Float16)b.y; v[6] = (_Float16)b.z; v[7] = (_Float16)b.w;
  } else {
#pragma unroll
    for (int i = 0; i < 8; ++i) v[i] = (_Float16)0.f;
  }
  *(half8*)(disp + (size_t)row * DDIM + t * 8) = v;
}

// ---------------- transpose + fp32->fp16 convert: in[R][Cc] -> out[Cc][R] ----------------
__global__ __launch_bounds__(256) void transpose_cvt(const float* __restrict__ in,
                                                     _Float16* __restrict__ out,
                                                     int R, int Cc) {
  __shared__ float tile[64][65];
  const size_t mat = (size_t)R * Cc;
  const float* ip = in + (size_t)blockIdx.z * mat;
  _Float16* op = out + (size_t)blockIdx.z * mat;
  const int r0 = blockIdx.y * 64, c0 = blockIdx.x * 64;
  const int tx = threadIdx.x & 63, ty = threadIdx.x >> 6;
#pragma unroll
  for (int i = 0; i < 16; ++i) {
    int rl = ty * 16 + i;
    tile[rl][tx] = ip[(size_t)(r0 + rl) * Cc + c0 + tx];
  }
  __syncthreads();
  const int cl = threadIdx.x >> 3;        // 0..31
  const int rch = (threadIdx.x & 7) * 8;  // row chunk base
#pragma unroll
  for (int pass = 0; pass < 2; ++pass) {
    int cc = cl + pass * 32;
    half8 v;
#pragma unroll
    for (int i = 0; i < 8; ++i) v[i] = (_Float16)tile[rch + i][cc];
    *(half8*)(op + (size_t)(c0 + cc) * R + r0 + rch) = v;
  }
}

// ---------------- grouped GEMM, m201 geometry: 256x256 tile, wave tile 128x64 ----
// C = A[z] @ B[z]^T (B stored [N][K]). fp16 in, fp32 acc. BK=32, 3 LDS buffers.
// 512 thr = 8 waves (2M x 4N). Per K-tile 2 phases; each phase: {ds_read frags,
// [burst / counted vmcnt], s_barrier, (compiler lgkm), setprio(1), 16 MFMA,
// setprio(0), s_barrier}. BURST(kt+2) at phase0 (its buffer drained at phase1 of
// kt-1); vmcnt(4) at phase1 keeps kt+2's 4 loads in flight (never 0 mid-loop).
// XOR swizzle (4-chunk space, chunk ^= row&3) on BOTH staging source and ds_read.
template <int KDIM, int NDIM, int SPLITK, bool FIRST>
__global__ __launch_bounds__(512, 2) void ffn_gemm_p(const _Float16* __restrict__ A_set,
                                                     const _Float16* __restrict__ B_set,
                                                     _Float16* __restrict__ Hout,
                                                     float* __restrict__ Y,
                                                     const int* __restrict__ s2t,
                                                     const float* __restrict__ rgate) {
  __shared__ __align__(16) _Float16 As[3 * 8192];   // 3 x [256][32]
  __shared__ __align__(16) _Float16 Bs[3 * 8192];   // 3 x [256][32]
  constexpr int TILES = 4 * (NDIM / 256);
  constexpr int PER_E = TILES * SPLITK;
  constexpr int NT_SEG = KDIM / 32 / SPLITK;
  const int wg = blockIdx.x;
  const int swz = (wg & 7) * PER_E + (wg >> 3);  // bijective; xcd == expert
  const int z = swz / PER_E;
  const int s2 = swz % PER_E;
  const int tile = s2 % TILES;
  const int kseg = s2 / TILES;
  const int m0 = (tile & 3) * 256;
  const int n0 = (tile >> 2) * 256;
  const int kt0 = kseg * NT_SEG;
  const int ktE = kt0 + NT_SEG;

  const int tid = threadIdx.x;
  const int trow = tid >> 2;                          // 0..127 staging row
  const int schunk = ((tid & 3) ^ (trow & 3)) * 8;    // pre-swizzled src k-offset

  const _Float16* Ae = A_set + (size_t)z * 1024 * KDIM;
  const _Float16* Be = B_set + (size_t)z * (size_t)NDIM * KDIM;

  const int lane = tid & 63;
  const int wid = tid >> 6;
  const int wr = wid >> 2, wc = wid & 3;              // 2M x 4N wave grid
  const int fr = lane & 15, fq = lane >> 4;
  const int wr128 = wr * 128, wc64 = wc * 64;

  f32x4 acc[8][4];
#pragma unroll
  for (int m = 0; m < 8; ++m)
#pragma unroll
    for (int n = 0; n < 4; ++n) acc[m][n] = {0.f, 0.f, 0.f, 0.f};

  auto BURST = [&](int kt) {   // 4 global_load_lds (A 2, B 2) into buf kt%3
    const int buf = kt % 3;
    const size_t kb = (size_t)kt * 32 + schunk;
#pragma unroll
    for (int j = 0; j < 2; ++j) {
      load_lds16(Ae + (size_t)(m0 + j * 128 + trow) * KDIM + kb,
                 As + buf * 8192 + j * 4096 + tid * 8);
      load_lds16(Be + (size_t)(n0 + j * 128 + trow) * KDIM + kb,
                 Bs + buf * 8192 + j * 4096 + tid * 8);
    }
  };

#define RD(base, r) (*(const half8*)((base) + (r) * 32 + (((fq) ^ ((r) & 3)) << 3)))
#define SF __builtin_amdgcn_sched_barrier(0)
#define BAR __builtin_amdgcn_s_barrier()

  // prologue: tiles kt0, kt0+1 in flight; wait kt0 landed (4 newest flying)
  BURST(kt0);
  if (kt0 + 1 < ktE) BURST(kt0 + 1);
  asm volatile("s_waitcnt vmcnt(4)" ::: "memory");
  SF; BAR; SF;

#pragma unroll 1
  for (int kt = kt0; kt < ktE; ++kt) {
    const _Float16* Ab = As + (kt % 3) * 8192;
    const _Float16* Bb = Bs + (kt % 3) * 8192;
    half8 af[4], bf[4];
    // ---- phase 0: m-half 0 ----
#pragma unroll
    for (int i = 0; i < 4; ++i) { int r = wr128 + i * 16 + fr; af[i] = RD(Ab, r); }
#pragma unroll
    for (int n = 0; n < 4; ++n) { int r = wc64 + n * 16 + fr; bf[n] = RD(Bb, r); }
    if (kt + 2 < ktE) BURST(kt + 2);
    SF; BAR; SF;
    __builtin_amdgcn_s_setprio(1);
#pragma unroll
    for (int i = 0; i < 4; ++i)
#pragma unroll
      for (int n = 0; n < 4; ++n)
        acc[i][n] = __builtin_amdgcn_mfma_f32_16x16x32_f16(af[i], bf[n], acc[i][n], 0, 0, 0);
    __builtin_amdgcn_s_setprio(0);
    SF; BAR; SF;
    // ---- phase 1: m-half 1 (bf reused) ----
#pragma unroll
    for (int i = 0; i < 4; ++i) { int r = wr128 + (4 + i) * 16 + fr; af[i] = RD(Ab, r); }
    if (kt + 2 < ktE) { asm volatile("s_waitcnt vmcnt(4)" ::: "memory"); }
    else              { asm volatile("s_waitcnt vmcnt(0)" ::: "memory"); }
    SF; BAR; SF;
    __builtin_amdgcn_s_setprio(1);
#pragma unroll
    for (int i = 0; i < 4; ++i)
#pragma unroll
      for (int n = 0; n < 4; ++n)
        acc[4 + i][n] = __builtin_amdgcn_mfma_f32_16x16x32_f16(af[i], bf[n], acc[4 + i][n], 0, 0, 0);
    __builtin_amdgcn_s_setprio(0);
    SF; BAR; SF;
  }
#undef RD
#undef SF
#undef BAR

  const int rb = wr128 + fq * 4;          // + m*16 + j
  const int cb = n0 + wc64 + fr;          // + n*16
  if (FIRST) {
#pragma unroll
    for (int m = 0; m < 8; ++m) {
#pragma unroll
      for (int j = 0; j < 4; ++j) {
        size_t row = (size_t)z * 1024 + m0 + rb + m * 16 + j;
#pragma unroll
        for (int n = 0; n < 4; ++n)
          Hout[row * (size_t)NDIM + cb + n * 16] = (_Float16)fmaxf(acc[m][n][j], 0.f);
      }
    }
  } else {
#pragma unroll
    for (int m = 0; m < 8; ++m) {
      int srow = z * CAP + m0 + rb + m * 16;
#pragma unroll
      for (int j = 0; j < 4; ++j) {
        int token = s2t[srow + j];
        if (token < 0) continue;
        float g = rgate[srow + j];
#pragma unroll
        for (int n = 0; n < 4; ++n) {
          if (SPLITK > 1)
            atomicAdd(&Y[(size_t)token * DDIM + cb + n * 16], acc[m][n][j] * g);
          else
            Y[(size_t)token * DDIM + cb + n * 16] = acc[m][n][j] * g;
        }
      }
    }
  }
}

extern "C" void kernel_launch(void* const* d_in, const int* in_sizes, int n_in,
                              void* d_out, int out_size, void* d_ws, size_t ws_size,
                              hipStream_t stream) {
  const float* x  = (const float*)d_in[0];
  const float* wg = (const float*)d_in[1];
  const float* w1 = (const float*)d_in[2];
  const float* w2 = (const float*)d_in[3];
  float* y = (float*)d_out;

  char* ws = (char*)d_ws;
  int*   eidx  = (int*)(ws);                 // 32 KB
  float* gtok  = (float*)(ws + 32768);       // 32 KB
  int*   s2t   = (int*)(ws + 65536);         // 32 KB
  float* rgate = (float*)(ws + 98304);       // 32 KB
  int*   cnt   = (int*)(ws + 131072);        // 4 KB
  int*   off   = (int*)(ws + 135168);        // 4 KB
  _Float16* disp = (_Float16*)(ws + 147456); // 16 MB
  char* big = ws + 147456 + (size_t)NEXP * CAP * DDIM * 2;
  _Float16* hbuf = (_Float16*)big;                  // [E][C][H] fp16, 64 MB
  _Float16* wt   = (_Float16*)(big + 67108864);     // shared w1t then w2t, 64 MB

  moe_gating<<<S_TOK / 4, 256, 0, stream>>>(x, wg, eidx, gtok);
  scanA<<<128, 64, 0, stream>>>(eidx, cnt);
  scanB<<<1, 64, 0, stream>>>(cnt, off);
  (void)hipMemsetAsync(s2t, 0xFF, 32768, stream);
  (void)hipMemsetAsync(rgate, 0, 32768, stream);
  scanC<<<128, 64, 0, stream>>>(eidx, gtok, off, s2t, rgate);
  moe_dispatch<<<NEXP * CAP, 128, 0, stream>>>(x, s2t, disp);
  (void)hipMemsetAsync(d_out, 0, (size_t)out_size * sizeof(float), stream);

  // GEMM1: [C,1024] x [1024,4096] -> relu -> hbuf fp16.  grid 8e x (4m x 16n) = 512
  transpose_cvt<<<dim3(HDIM / 64, DDIM / 64, NEXP), 256, 0, stream>>>(w1, wt, DDIM, HDIM);
  ffn_gemm_p<DDIM, HDIM, 1, true><<<512, 512, 0, stream>>>(
      disp, wt, hbuf, nullptr, nullptr, nullptr);

  // GEMM2: [C,4096] x [4096,1024] -> scatter-add to y.  split-K=2: 8e x 16t x 2k = 256
  transpose_cvt<<<dim3(DDIM / 64, HDIM / 64, NEXP), 256, 0, stream>>>(w2, wt, HDIM, DDIM);
  ffn_gemm_p<HDIM, DDIM, 2, false><<<256, 512, 0, stream>>>(
      hbuf, wt, nullptr, y, s2t, rgate);
}

// Round 7
// 324.015 us; speedup vs baseline: 1.1553x; 1.0725x over previous
//
#include <hip/hip_runtime.h>
#include <hip/hip_fp16.h>

#define S_TOK 8192
#define DDIM  1024
#define HDIM  4096
#define NEXP  8
#define CAP   1024

typedef __attribute__((ext_vector_type(8))) _Float16 half8;
typedef __attribute__((ext_vector_type(4))) float f32x4;

__device__ __forceinline__ void load_lds16(const _Float16* g, _Float16* l) {
  __builtin_amdgcn_global_load_lds(
      (const __attribute__((address_space(1))) unsigned int*)g,
      (__attribute__((address_space(3))) unsigned int*)l, 16, 0, 0);
}

// ---------------- gating: logits = x @ wg, softmax, top-1 ----------------
__global__ __launch_bounds__(256) void moe_gating(const float* __restrict__ x,
                                                  const float* __restrict__ wg,
                                                  int* __restrict__ eidx,
                                                  float* __restrict__ gtok) {
  const int s = blockIdx.x * 4 + (threadIdx.x >> 6);
  const int lane = threadIdx.x & 63;
  const float* xr = x + (size_t)s * DDIM;
  float acc[NEXP];
#pragma unroll
  for (int e = 0; e < NEXP; ++e) acc[e] = 0.f;
  for (int d = lane; d < DDIM; d += 64) {
    float xv = xr[d];
    const float4* wrow = (const float4*)(wg + (size_t)d * NEXP);
    float4 w0 = wrow[0], w1v = wrow[1];
    acc[0] += xv * w0.x;  acc[1] += xv * w0.y;
    acc[2] += xv * w0.z;  acc[3] += xv * w0.w;
    acc[4] += xv * w1v.x; acc[5] += xv * w1v.y;
    acc[6] += xv * w1v.z; acc[7] += xv * w1v.w;
  }
#pragma unroll
  for (int off = 32; off > 0; off >>= 1) {
#pragma unroll
    for (int e = 0; e < NEXP; ++e) acc[e] += __shfl_down(acc[e], off);
  }
  if (lane == 0) {
    int best = 0; float bv = acc[0];
#pragma unroll
    for (int e = 1; e < NEXP; ++e) if (acc[e] > bv) { bv = acc[e]; best = e; }
    float sum = 0.f;
#pragma unroll
    for (int e = 0; e < NEXP; ++e) sum += expf(acc[e] - bv);
    eidx[s] = best;
    gtok[s] = 1.f / sum;   // exp(best - max) == 1
  }
}

// ---------------- hierarchical ordered slot assignment ----------------
__global__ __launch_bounds__(64) void scanA(const int* __restrict__ eidx,
                                            int* __restrict__ cnt) {
  const int blk = blockIdx.x;        // 128 blocks x 64 tokens
  const int lane = threadIdx.x;
  int e = eidx[blk * 64 + lane];
#pragma unroll
  for (int w = 0; w < NEXP; ++w) {
    unsigned long long m = __ballot(e == w);
    if (lane == 0) cnt[blk * NEXP + w] = __popcll(m);
  }
}

// 8 waves, wave w = expert w; 64-lane shfl exclusive scan over 128 block-counts
__global__ __launch_bounds__(512) void scanB(const int* __restrict__ cnt,
                                             int* __restrict__ off) {
  const int w = threadIdx.x >> 6;
  const int l = threadIdx.x & 63;
  int c0 = cnt[(2 * l) * NEXP + w];
  int c1 = cnt[(2 * l + 1) * NEXP + w];
  int s = c0 + c1;
  int run = s;
#pragma unroll
  for (int d = 1; d < 64; d <<= 1) {
    int up = __shfl_up(run, d);
    if (l >= d) run += up;
  }
  int excl = run - s;
  off[(2 * l) * NEXP + w] = excl;
  off[(2 * l + 1) * NEXP + w] = excl + c0;
}

__global__ __launch_bounds__(64) void scanC(const int* __restrict__ eidx,
                                            const float* __restrict__ gtok,
                                            const int* __restrict__ off,
                                            int* __restrict__ s2t,
                                            float* __restrict__ rgate) {
  const int blk = blockIdx.x;
  const int lane = threadIdx.x;
  const int tok = blk * 64 + lane;
  int e = eidx[tok];
  float g = gtok[tok];
  const unsigned long long below = (1ull << lane) - 1ull;
#pragma unroll
  for (int w = 0; w < NEXP; ++w) {
    unsigned long long m = __ballot(e == w);
    if (e == w) {
      int slot = off[blk * NEXP + w] + __popcll(m & below);
      if (slot < CAP) { s2t[w * CAP + slot] = tok; rgate[w * CAP + slot] = g; }
    }
  }
}

// ---------------- dispatch: gather kept tokens, fp32 -> fp16 ----------------
__global__ __launch_bounds__(128) void moe_dispatch(const float* __restrict__ x,
                                                    const int* __restrict__ s2t,
                                                    _Float16* __restrict__ disp) {
  const int row = blockIdx.x;
  const int t = threadIdx.x;
  const int token = s2t[row];
  half8 v;
  if (token >= 0) {
    const float4* xr = (const float4*)(x + (size_t)token * DDIM);
    float4 a = xr[2 * t], b = xr[2 * t + 1];
    v[0] = (_Float16)a.x; v[1] = (_Float16)a.y; v[2] = (_Float16)a.z; v[3] = (_Float16)a.w;
    v[4] = (_Float16)b.x; v[5] = (_Float16)b.y; v[6] = (_Float16)b.z; v[7] = (_Float16)b.w;
  } else {
#pragma unroll
    for (int i = 0; i < 8; ++i) v[i] = (_Float16)0.f;
  }
  *(half8*)(disp + (size_t)row * DDIM + t * 8) = v;
}

// ---------------- transpose + fp32->fp16 convert: in[R][Cc] -> out[Cc][R] ----------------
__global__ __launch_bounds__(256) void transpose_cvt(const float* __restrict__ in,
                                                     _Float16* __restrict__ out,
                                                     int R, int Cc) {
  __shared__ float tile[64][65];
  const size_t mat = (size_t)R * Cc;
  const float* ip = in + (size_t)blockIdx.z * mat;
  _Float16* op = out + (size_t)blockIdx.z * mat;
  const int r0 = blockIdx.y * 64, c0 = blockIdx.x * 64;
  const int tx = threadIdx.x & 63, ty = threadIdx.x >> 6;
#pragma unroll
  for (int i = 0; i < 16; ++i) {
    int rl = ty * 16 + i;
    tile[rl][tx] = ip[(size_t)(r0 + rl) * Cc + c0 + tx];
  }
  __syncthreads();
  const int cl = threadIdx.x >> 3;        // 0..31
  const int rch = (threadIdx.x & 7) * 8;  // row chunk base
#pragma unroll
  for (int pass = 0; pass < 2; ++pass) {
    int cc = cl + pass * 32;
    half8 v;
#pragma unroll
    for (int i = 0; i < 8; ++i) v[i] = (_Float16)tile[rch + i][cc];
    *(half8*)(op + (size_t)(c0 + cc) * R + r0 + rch) = v;
  }
}

// ---------------- grouped GEMM: full m201 8-phase template, fp16 ----------------
// C = A[z] @ B[z]^T (B stored [N][K]). BM=BN=256, BK=64, 512 thr = 8 waves (2Mx4N).
// LDS: A,B each [dbuf(2) x half(2)][128][64] fp16 = 64 KB -> 128 KB total.
// 8 phases per K-tile pair (ka=d0, kb=d1); phase p: quadrant q=p&3=(mh,nh), kk=p>>2.
// Phase touches ONLY A-half mh, B-half nh of dbuf kk. Wave owns 64x32 of each
// block-quadrant; acc[q][4][2]. Frag regs reused: af read at q0/q2, bfA at q0
// (used q0,q2), bfB at q1 (used q1,q3) -> per-phase ds_reads 12/4/8/0.
// Staging: 1-2 half-tiles per phase (2 gload_lds each, 16B, linear LDS dest,
// source k-chunk pre-swizzled c^=(r&7); ds_read applies same XOR -> 0 conflicts).
// Slots: p0: A-d1h1,B-d1h1 (kb);  p2: A-d0h0 (ka+2); p3: B-d0h0 (ka+2) + vmcnt;
//        p4: A-d0h1,B-d0h1 (ka+2); p6: A-d1h0 (kb+2); p7: B-d1h0 (kb+2) + vmcnt.
// Waits (derived): end-p3 vmcnt(4) -> p0's 4 loads landed (read p5/p6); last iter
// vmcnt(0). end-p7 vmcnt(4) -> loads through p4 landed (read next p0-p3).
template <int KDIM, int NDIM, int SPLITK, bool FIRST>
__global__ __launch_bounds__(512, 2) void ffn_gemm_m(const _Float16* __restrict__ A_set,
                                                     const _Float16* __restrict__ B_set,
                                                     _Float16* __restrict__ Hout,
                                                     float* __restrict__ Y,
                                                     const int* __restrict__ s2t,
                                                     const float* __restrict__ rgate) {
  __shared__ __align__(16) _Float16 As[4 * 8192];   // [d*2+h][128][64]
  __shared__ __align__(16) _Float16 Bs[4 * 8192];
  constexpr int TILES = 4 * (NDIM / 256);
  constexpr int PER_E = TILES * SPLITK;
  constexpr int NTSEG = KDIM / 64 / SPLITK;   // K-tiles per segment (even)
  constexpr int NI = NTSEG / 2;               // iterations (K-tile pairs)
  const int wg = blockIdx.x;
  const int swz = (wg & 7) * PER_E + (wg >> 3);   // bijective; xcd == expert
  const int z = swz / PER_E;
  const int s2 = swz % PER_E;
  const int tile = s2 % TILES;
  const int kseg = s2 / TILES;
  const int m0 = (tile & 3) * 256;
  const int n0 = (tile >> 2) * 256;
  const int kt0 = kseg * NTSEG;

  const int tid = threadIdx.x;
  const _Float16* Ae = A_set + (size_t)z * 1024 * KDIM;
  const _Float16* Be = B_set + (size_t)z * (size_t)NDIM * KDIM;

  // staging: slot s = j*512+tid -> row r = j*64+(tid>>3), chunk c = tid&7
  const int sr0 = tid >> 3;
  const int sc0 = tid & 7;
  auto STG = [&](const _Float16* gbase, _Float16* lbase, int rowbase, int kt) {
#pragma unroll
    for (int j = 0; j < 2; ++j) {
      int r = j * 64 + sr0;
      load_lds16(gbase + (size_t)(rowbase + r) * KDIM + kt * 64 + ((sc0 ^ (r & 7)) << 3),
                 lbase + j * 4096 + tid * 8);
    }
  };

  const int lane = tid & 63, wid = tid >> 6;
  const int fr = lane & 15, fq = lane >> 4;
  const int war = (wid >> 2) * 64;   // wave A-row base within half
  const int wbr = (wid & 3) * 32;    // wave B-row base within half
  int offA[4][2], offB[2][2];
#pragma unroll
  for (int m = 0; m < 4; ++m)
#pragma unroll
    for (int ks = 0; ks < 2; ++ks) {
      int r = war + m * 16 + fr, c = ks * 4 + fq;
      offA[m][ks] = r * 64 + ((c ^ (r & 7)) << 3);
    }
#pragma unroll
  for (int n = 0; n < 2; ++n)
#pragma unroll
    for (int ks = 0; ks < 2; ++ks) {
      int r = wbr + n * 16 + fr, c = ks * 4 + fq;
      offB[n][ks] = r * 64 + ((c ^ (r & 7)) << 3);
    }

  f32x4 acc[4][4][2];
#pragma unroll
  for (int q = 0; q < 4; ++q)
#pragma unroll
    for (int m = 0; m < 4; ++m)
#pragma unroll
      for (int n = 0; n < 2; ++n) acc[q][m][n] = {0.f, 0.f, 0.f, 0.f};

#define SF __builtin_amdgcn_sched_barrier(0)
#define BARS SF; __builtin_amdgcn_s_barrier(); SF
#define RDA(KK, MH) { _Pragma("unroll") for (int m = 0; m < 4; ++m) { \
      af[m][0] = *(const half8*)(As + ((KK) * 2 + (MH)) * 8192 + offA[m][0]); \
      af[m][1] = *(const half8*)(As + ((KK) * 2 + (MH)) * 8192 + offA[m][1]); } }
#define RDB(KK, NH, BF) { _Pragma("unroll") for (int n = 0; n < 2; ++n) { \
      BF[n][0] = *(const half8*)(Bs + ((KK) * 2 + (NH)) * 8192 + offB[n][0]); \
      BF[n][1] = *(const half8*)(Bs + ((KK) * 2 + (NH)) * 8192 + offB[n][1]); } }
#define MM16(Q, BF) { __builtin_amdgcn_s_setprio(1); \
    _Pragma("unroll") for (int ks = 0; ks < 2; ++ks) \
    _Pragma("unroll") for (int m = 0; m < 4; ++m) \
    _Pragma("unroll") for (int n = 0; n < 2; ++n) \
      acc[Q][m][n] = __builtin_amdgcn_mfma_f32_16x16x32_f16(af[m][ks], BF[n][ks], acc[Q][m][n], 0, 0, 0); \
    __builtin_amdgcn_s_setprio(0); }

  // prologue: K-tile kt0 (all 4 halves), kt0+1 (h0 halves); oldest 8 must land
  STG(Ae, As + 0 * 8192, m0 + 0,   kt0);
  STG(Be, Bs + 0 * 8192, n0 + 0,   kt0);
  STG(Ae, As + 1 * 8192, m0 + 128, kt0);
  STG(Be, Bs + 1 * 8192, n0 + 128, kt0);
  STG(Ae, As + 2 * 8192, m0 + 0,   kt0 + 1);
  STG(Be, Bs + 2 * 8192, n0 + 0,   kt0 + 1);
  asm volatile("s_waitcnt vmcnt(4)" ::: "memory");
  BARS;

#pragma unroll 1
  for (int i = 0; i < NI; ++i) {
    const int ka = kt0 + 2 * i;
    const bool more = (i + 1 < NI);
    half8 af[4][2], bfA[2][2], bfB[2][2];
    // ---- p0: q(0,0) of ka ----
    RDA(0, 0); RDB(0, 0, bfA);
    STG(Ae, As + 3 * 8192, m0 + 128, ka + 1);   // A d1h1 (kb)
    STG(Be, Bs + 3 * 8192, n0 + 128, ka + 1);   // B d1h1 (kb)
    BARS; MM16(0, bfA); BARS;
    // ---- p1: q(0,1) ----
    RDB(0, 1, bfB);
    BARS; MM16(1, bfB); BARS;
    // ---- p2: q(1,0) ----
    RDA(0, 1);
    if (more) STG(Ae, As + 0 * 8192, m0 + 0, ka + 2);   // A d0h0
    BARS; MM16(2, bfA); BARS;
    // ---- p3: q(1,1) ----
    if (more) {
      STG(Be, Bs + 0 * 8192, n0 + 0, ka + 2);           // B d0h0
      asm volatile("s_waitcnt vmcnt(4)" ::: "memory");
    } else {
      asm volatile("s_waitcnt vmcnt(0)" ::: "memory");
    }
    BARS; MM16(3, bfB); BARS;
    // ---- p4: q(0,0) of kb ----
    RDA(1, 0); RDB(1, 0, bfA);
    if (more) {
      STG(Ae, As + 1 * 8192, m0 + 128, ka + 2);         // A d0h1
      STG(Be, Bs + 1 * 8192, n0 + 128, ka + 2);         // B d0h1
    }
    BARS; MM16(0, bfA); BARS;
    // ---- p5: q(0,1) ----
    RDB(1, 1, bfB);
    BARS; MM16(1, bfB); BARS;
    // ---- p6: q(1,0) ----
    RDA(1, 1);
    if (more) STG(Ae, As + 2 * 8192, m0 + 0, ka + 3);   // A d1h0
    BARS; MM16(2, bfA); BARS;
    // ---- p7: q(1,1) ----
    if (more) {
      STG(Be, Bs + 2 * 8192, n0 + 0, ka + 3);           // B d1h0
      asm volatile("s_waitcnt vmcnt(4)" ::: "memory");
    }
    BARS; MM16(3, bfB); BARS;
  }
#undef MM16
#undef RDB
#undef RDA
#undef BARS
#undef SF

  // epilogue
#pragma unroll
  for (int q = 0; q < 4; ++q) {
    const int mh = q >> 1, nh = q & 1;
#pragma unroll
    for (int m = 0; m < 4; ++m) {
      const int rowb = m0 + mh * 128 + war + m * 16 + fq * 4;
      const int colb = n0 + nh * 128 + wbr + fr;
      if (FIRST) {
#pragma unroll
        for (int j = 0; j < 4; ++j) {
          size_t row = (size_t)z * 1024 + rowb + j;
#pragma unroll
          for (int n = 0; n < 2; ++n)
            Hout[row * (size_t)NDIM + colb + n * 16] = (_Float16)fmaxf(acc[q][m][n][j], 0.f);
        }
      } else {
        const int srow = z * CAP + rowb;
#pragma unroll
        for (int j = 0; j < 4; ++j) {
          int token = s2t[srow + j];
          if (token < 0) continue;
          float g = rgate[srow + j];
#pragma unroll
          for (int n = 0; n < 2; ++n) {
            if (SPLITK > 1)
              atomicAdd(&Y[(size_t)token * DDIM + colb + n * 16], acc[q][m][n][j] * g);
            else
              Y[(size_t)token * DDIM + colb + n * 16] = acc[q][m][n][j] * g;
          }
        }
      }
    }
  }
}

extern "C" void kernel_launch(void* const* d_in, const int* in_sizes, int n_in,
                              void* d_out, int out_size, void* d_ws, size_t ws_size,
                              hipStream_t stream) {
  const float* x  = (const float*)d_in[0];
  const float* wg = (const float*)d_in[1];
  const float* w1 = (const float*)d_in[2];
  const float* w2 = (const float*)d_in[3];
  float* y = (float*)d_out;

  char* ws = (char*)d_ws;
  int*   eidx  = (int*)(ws);                 // 32 KB
  float* gtok  = (float*)(ws + 32768);       // 32 KB
  int*   s2t   = (int*)(ws + 65536);         // 32 KB
  float* rgate = (float*)(ws + 98304);       // 32 KB
  int*   cnt   = (int*)(ws + 131072);        // 4 KB
  int*   off   = (int*)(ws + 135168);        // 4 KB
  _Float16* disp = (_Float16*)(ws + 147456); // 16 MB
  char* big = ws + 147456 + (size_t)NEXP * CAP * DDIM * 2;
  _Float16* hbuf = (_Float16*)big;                  // [E][C][H] fp16, 64 MB
  _Float16* wt   = (_Float16*)(big + 67108864);     // shared w1t then w2t, 64 MB

  moe_gating<<<S_TOK / 4, 256, 0, stream>>>(x, wg, eidx, gtok);
  scanA<<<128, 64, 0, stream>>>(eidx, cnt);
  scanB<<<1, 512, 0, stream>>>(cnt, off);
  (void)hipMemsetAsync(s2t, 0xFF, 32768, stream);
  (void)hipMemsetAsync(rgate, 0, 32768, stream);
  scanC<<<128, 64, 0, stream>>>(eidx, gtok, off, s2t, rgate);
  moe_dispatch<<<NEXP * CAP, 128, 0, stream>>>(x, s2t, disp);
  (void)hipMemsetAsync(d_out, 0, (size_t)out_size * sizeof(float), stream);

  // GEMM1: [C,1024] x [1024,4096] -> relu -> hbuf fp16.  8e x (4m x 16n) = 512 blocks
  transpose_cvt<<<dim3(HDIM / 64, DDIM / 64, NEXP), 256, 0, stream>>>(w1, wt, DDIM, HDIM);
  ffn_gemm_m<DDIM, HDIM, 1, true><<<512, 512, 0, stream>>>(
      disp, wt, hbuf, nullptr, nullptr, nullptr);

  // GEMM2: [C,4096] x [4096,1024] -> scatter-add to y.  8e x 16t x 2k = 256 blocks
  transpose_cvt<<<dim3(DDIM / 64, HDIM / 64, NEXP), 256, 0, stream>>>(w2, wt, HDIM, DDIM);
  ffn_gemm_m<HDIM, DDIM, 2, false><<<256, 512, 0, stream>>>(
      hbuf, wt, nullptr, y, s2t, rgate);
}

// Round 8
// 320.202 us; speedup vs baseline: 1.1690x; 1.0119x over previous
//
#include <hip/hip_runtime.h>
#include <hip/hip_fp16.h>

#define S_TOK 8192
#define DDIM  1024
#define HDIM  4096
#define NEXP  8
#define CAP   1024

typedef __attribute__((ext_vector_type(8))) _Float16 half8;
typedef __attribute__((ext_vector_type(4))) float f32x4;

__device__ __forceinline__ void load_lds16(const _Float16* g, _Float16* l) {
  __builtin_amdgcn_global_load_lds(
      (const __attribute__((address_space(1))) unsigned int*)g,
      (__attribute__((address_space(3))) unsigned int*)l, 16, 0, 0);
}

// ---------------- gating: logits = x @ wg, softmax, top-1 ----------------
__global__ __launch_bounds__(256) void moe_gating(const float* __restrict__ x,
                                                  const float* __restrict__ wg,
                                                  int* __restrict__ eidx,
                                                  float* __restrict__ gtok) {
  const int s = blockIdx.x * 4 + (threadIdx.x >> 6);
  const int lane = threadIdx.x & 63;
  const float* xr = x + (size_t)s * DDIM;
  float acc[NEXP];
#pragma unroll
  for (int e = 0; e < NEXP; ++e) acc[e] = 0.f;
  for (int d = lane; d < DDIM; d += 64) {
    float xv = xr[d];
    const float4* wrow = (const float4*)(wg + (size_t)d * NEXP);
    float4 w0 = wrow[0], w1v = wrow[1];
    acc[0] += xv * w0.x;  acc[1] += xv * w0.y;
    acc[2] += xv * w0.z;  acc[3] += xv * w0.w;
    acc[4] += xv * w1v.x; acc[5] += xv * w1v.y;
    acc[6] += xv * w1v.z; acc[7] += xv * w1v.w;
  }
#pragma unroll
  for (int off = 32; off > 0; off >>= 1) {
#pragma unroll
    for (int e = 0; e < NEXP; ++e) acc[e] += __shfl_down(acc[e], off);
  }
  if (lane == 0) {
    int best = 0; float bv = acc[0];
#pragma unroll
    for (int e = 1; e < NEXP; ++e) if (acc[e] > bv) { bv = acc[e]; best = e; }
    float sum = 0.f;
#pragma unroll
    for (int e = 0; e < NEXP; ++e) sum += expf(acc[e] - bv);
    eidx[s] = best;
    gtok[s] = 1.f / sum;   // exp(best - max) == 1
  }
}

// ---------------- hierarchical ordered slot assignment ----------------
__global__ __launch_bounds__(64) void scanA(const int* __restrict__ eidx,
                                            int* __restrict__ cnt) {
  const int blk = blockIdx.x;        // 128 blocks x 64 tokens
  const int lane = threadIdx.x;
  int e = eidx[blk * 64 + lane];
#pragma unroll
  for (int w = 0; w < NEXP; ++w) {
    unsigned long long m = __ballot(e == w);
    if (lane == 0) cnt[blk * NEXP + w] = __popcll(m);
  }
}

// 8 waves, wave w = expert w; 64-lane shfl exclusive scan over 128 block-counts
__global__ __launch_bounds__(512) void scanB(const int* __restrict__ cnt,
                                             int* __restrict__ off) {
  const int w = threadIdx.x >> 6;
  const int l = threadIdx.x & 63;
  int c0 = cnt[(2 * l) * NEXP + w];
  int c1 = cnt[(2 * l + 1) * NEXP + w];
  int s = c0 + c1;
  int run = s;
#pragma unroll
  for (int d = 1; d < 64; d <<= 1) {
    int up = __shfl_up(run, d);
    if (l >= d) run += up;
  }
  int excl = run - s;
  off[(2 * l) * NEXP + w] = excl;
  off[(2 * l + 1) * NEXP + w] = excl + c0;
}

__global__ __launch_bounds__(64) void scanC(const int* __restrict__ eidx,
                                            const float* __restrict__ gtok,
                                            const int* __restrict__ off,
                                            int* __restrict__ s2t,
                                            float* __restrict__ rgate) {
  const int blk = blockIdx.x;
  const int lane = threadIdx.x;
  const int tok = blk * 64 + lane;
  int e = eidx[tok];
  float g = gtok[tok];
  const unsigned long long below = (1ull << lane) - 1ull;
#pragma unroll
  for (int w = 0; w < NEXP; ++w) {
    unsigned long long m = __ballot(e == w);
    if (e == w) {
      int slot = off[blk * NEXP + w] + __popcll(m & below);
      if (slot < CAP) { s2t[w * CAP + slot] = tok; rgate[w * CAP + slot] = g; }
    }
  }
}

// ---------------- dispatch: gather kept tokens, fp32 -> fp16 ----------------
__global__ __launch_bounds__(128) void moe_dispatch(const float* __restrict__ x,
                                                    const int* __restrict__ s2t,
                                                    _Float16* __restrict__ disp) {
  const int row = blockIdx.x;
  const int t = threadIdx.x;
  const int token = s2t[row];
  half8 v;
  if (token >= 0) {
    const float4* xr = (const float4*)(x + (size_t)token * DDIM);
    float4 a = xr[2 * t], b = xr[2 * t + 1];
    v[0] = (_Float16)a.x; v[1] = (_Float16)a.y; v[2] = (_Float16)a.z; v[3] = (_Float16)a.w;
    v[4] = (_Float16)b.x; v[5] = (_Float16)b.y; v[6] = (_Float16)b.z; v[7] = (_Float16)b.w;
  } else {
#pragma unroll
    for (int i = 0; i < 8; ++i) v[i] = (_Float16)0.f;
  }
  *(half8*)(disp + (size_t)row * DDIM + t * 8) = v;
}

// ---------------- transpose + fp32->fp16 convert: in[R][Cc] -> out[Cc][R] ----------------
__global__ __launch_bounds__(256) void transpose_cvt(const float* __restrict__ in,
                                                     _Float16* __restrict__ out,
                                                     int R, int Cc) {
  __shared__ float tile[64][65];
  const size_t mat = (size_t)R * Cc;
  const float* ip = in + (size_t)blockIdx.z * mat;
  _Float16* op = out + (size_t)blockIdx.z * mat;
  const int r0 = blockIdx.y * 64, c0 = blockIdx.x * 64;
  const int tx = threadIdx.x & 63, ty = threadIdx.x >> 6;
#pragma unroll
  for (int i = 0; i < 16; ++i) {
    int rl = ty * 16 + i;
    tile[rl][tx] = ip[(size_t)(r0 + rl) * Cc + c0 + tx];
  }
  __syncthreads();
  const int cl = threadIdx.x >> 3;        // 0..31
  const int rch = (threadIdx.x & 7) * 8;  // row chunk base
#pragma unroll
  for (int pass = 0; pass < 2; ++pass) {
    int cc = cl + pass * 32;
    half8 v;
#pragma unroll
    for (int i = 0; i < 8; ++i) v[i] = (_Float16)tile[rch + i][cc];
    *(half8*)(op + (size_t)(c0 + cc) * R + r0 + rch) = v;
  }
}

// ---------------- grouped GEMM: m201 8-phase template, minimal pinning ----------------
// C = A[z] @ B[z]^T (B stored [N][K]). BM=BN=256, BK=64, 512 thr = 8 waves (2Mx4N).
// LDS: A,B each [dbuf(2) x half(2)][128][64] fp16 = 64 KB -> 128 KB total.
// 8 phases per K-tile pair; phase p: quadrant q=p&3=(mh,nh) of dbuf kk=p>>2.
// Per phase: {ds_read frags, stage EXACTLY 1 half-tile (2 gload_lds),
// [counted vmcnt at p3/p7 + ONE sched_barrier], s_barrier, setprio(1),
// 16 MFMA, setprio(0), s_barrier}. NO other sched_barriers (m141 lesson).
// Stage slots: p0:A-d1h1(kb) p1:B-d1h1(kb) p2:A-d0h0(ka+2) p3:B-d0h0(ka+2)+vmcnt(4)
//              p4:A-d0h1(ka+2) p5:B-d0h1(ka+2) p6:A-d1h0(ka+3) p7:B-d1h0(ka+3)+vmcnt(4)
// Wait derivation: p3's vmcnt(4) leaves p2,p3 (4 loads) in flight -> p0,p1 landed
// (read at p5/p6). p7's vmcnt(4) leaves p6,p7 -> p2..p5 landed (read next p0..p2).
// Last iter: p3 -> vmcnt(0) (no p2/p3 stages), p7 -> no wait.
// Buffer-reuse safety: stage into buf b only after the phase-close barrier of b's
// last reader (reader's lgkm-wait precedes its MFMA which precedes that barrier).
// XOR swizzle (16B-chunk ^= row&7) on BOTH staging source and ds_read offsets.
template <int KDIM, int NDIM, int SPLITK, bool FIRST>
__global__ __launch_bounds__(512, 2) void ffn_gemm_m(const _Float16* __restrict__ A_set,
                                                     const _Float16* __restrict__ B_set,
                                                     _Float16* __restrict__ Hout,
                                                     float* __restrict__ Y,
                                                     const int* __restrict__ s2t,
                                                     const float* __restrict__ rgate) {
  __shared__ __align__(16) _Float16 As[4 * 8192];   // [d*2+h][128][64]
  __shared__ __align__(16) _Float16 Bs[4 * 8192];
  constexpr int TILES = 4 * (NDIM / 256);
  constexpr int PER_E = TILES * SPLITK;
  constexpr int NTSEG = KDIM / 64 / SPLITK;   // K-tiles per segment (even)
  constexpr int NI = NTSEG / 2;               // iterations (K-tile pairs)
  const int wg = blockIdx.x;
  const int swz = (wg & 7) * PER_E + (wg >> 3);   // bijective; xcd == expert
  const int z = swz / PER_E;
  const int s2 = swz % PER_E;
  const int tile = s2 % TILES;
  const int kseg = s2 / TILES;
  const int m0 = (tile & 3) * 256;
  const int n0 = (tile >> 2) * 256;
  const int kt0 = kseg * NTSEG;

  const int tid = threadIdx.x;
  const _Float16* Ae = A_set + (size_t)z * 1024 * KDIM;
  const _Float16* Be = B_set + (size_t)z * (size_t)NDIM * KDIM;

  const int sr0 = tid >> 3;
  const int sc0 = tid & 7;
  auto STG = [&](const _Float16* gbase, _Float16* lbase, int rowbase, int kt) {
#pragma unroll
    for (int j = 0; j < 2; ++j) {
      int r = j * 64 + sr0;
      load_lds16(gbase + (size_t)(rowbase + r) * KDIM + kt * 64 + ((sc0 ^ (r & 7)) << 3),
                 lbase + j * 4096 + tid * 8);
    }
  };

  const int lane = tid & 63, wid = tid >> 6;
  const int fr = lane & 15, fq = lane >> 4;
  const int war = (wid >> 2) * 64;   // wave A-row base within half
  const int wbr = (wid & 3) * 32;    // wave B-row base within half
  int offA[4][2], offB[2][2];
#pragma unroll
  for (int m = 0; m < 4; ++m)
#pragma unroll
    for (int ks = 0; ks < 2; ++ks) {
      int r = war + m * 16 + fr, c = ks * 4 + fq;
      offA[m][ks] = r * 64 + ((c ^ (r & 7)) << 3);
    }
#pragma unroll
  for (int n = 0; n < 2; ++n)
#pragma unroll
    for (int ks = 0; ks < 2; ++ks) {
      int r = wbr + n * 16 + fr, c = ks * 4 + fq;
      offB[n][ks] = r * 64 + ((c ^ (r & 7)) << 3);
    }

  f32x4 acc[4][4][2];
#pragma unroll
  for (int q = 0; q < 4; ++q)
#pragma unroll
    for (int m = 0; m < 4; ++m)
#pragma unroll
      for (int n = 0; n < 2; ++n) acc[q][m][n] = {0.f, 0.f, 0.f, 0.f};

#define BAR __builtin_amdgcn_s_barrier()
#define PUBFENCE __builtin_amdgcn_sched_barrier(0)
#define RDA(KK, MH) { _Pragma("unroll") for (int m = 0; m < 4; ++m) { \
      af[m][0] = *(const half8*)(As + ((KK) * 2 + (MH)) * 8192 + offA[m][0]); \
      af[m][1] = *(const half8*)(As + ((KK) * 2 + (MH)) * 8192 + offA[m][1]); } }
#define RDB(KK, NH, BF) { _Pragma("unroll") for (int n = 0; n < 2; ++n) { \
      BF[n][0] = *(const half8*)(Bs + ((KK) * 2 + (NH)) * 8192 + offB[n][0]); \
      BF[n][1] = *(const half8*)(Bs + ((KK) * 2 + (NH)) * 8192 + offB[n][1]); } }
#define MM16(Q, BF) { __builtin_amdgcn_s_setprio(1); \
    _Pragma("unroll") for (int ks = 0; ks < 2; ++ks) \
    _Pragma("unroll") for (int m = 0; m < 4; ++m) \
    _Pragma("unroll") for (int n = 0; n < 2; ++n) \
      acc[Q][m][n] = __builtin_amdgcn_mfma_f32_16x16x32_f16(af[m][ks], BF[n][ks], acc[Q][m][n], 0, 0, 0); \
    __builtin_amdgcn_s_setprio(0); }

  // prologue: K-tile kt0 (4 halves) + kt0+1 (h0 halves); drain kt0's 8 loads
  STG(Ae, As + 0 * 8192, m0 + 0,   kt0);
  STG(Be, Bs + 0 * 8192, n0 + 0,   kt0);
  STG(Ae, As + 1 * 8192, m0 + 128, kt0);
  STG(Be, Bs + 1 * 8192, n0 + 128, kt0);
  STG(Ae, As + 2 * 8192, m0 + 0,   kt0 + 1);
  STG(Be, Bs + 2 * 8192, n0 + 0,   kt0 + 1);
  asm volatile("s_waitcnt vmcnt(4)" ::: "memory");
  PUBFENCE;
  BAR;

#pragma unroll 1
  for (int i = 0; i < NI; ++i) {
    const int ka = kt0 + 2 * i;
    const bool more = (i + 1 < NI);
    half8 af[4][2], bfA[2][2], bfB[2][2];
    // ---- p0: q(0,0) of ka ----
    RDA(0, 0); RDB(0, 0, bfA);
    STG(Ae, As + 3 * 8192, m0 + 128, ka + 1);
    BAR; MM16(0, bfA); BAR;
    // ---- p1: q(0,1) ----
    RDB(0, 1, bfB);
    STG(Be, Bs + 3 * 8192, n0 + 128, ka + 1);
    BAR; MM16(1, bfB); BAR;
    // ---- p2: q(1,0) ----
    RDA(0, 1);
    if (more) STG(Ae, As + 0 * 8192, m0 + 0, ka + 2);
    BAR; MM16(2, bfA); BAR;
    // ---- p3: q(1,1) ----
    if (more) {
      STG(Be, Bs + 0 * 8192, n0 + 0, ka + 2);
      asm volatile("s_waitcnt vmcnt(4)" ::: "memory");
    } else {
      asm volatile("s_waitcnt vmcnt(0)" ::: "memory");
    }
    PUBFENCE;
    BAR; MM16(3, bfB); BAR;
    // ---- p4: q(0,0) of kb ----
    RDA(1, 0); RDB(1, 0, bfA);
    if (more) STG(Ae, As + 1 * 8192, m0 + 128, ka + 2);
    BAR; MM16(0, bfA); BAR;
    // ---- p5: q(0,1) ----
    RDB(1, 1, bfB);
    if (more) STG(Be, Bs + 1 * 8192, n0 + 128, ka + 2);
    BAR; MM16(1, bfB); BAR;
    // ---- p6: q(1,0) ----
    RDA(1, 1);
    if (more) STG(Ae, As + 2 * 8192, m0 + 0, ka + 3);
    BAR; MM16(2, bfA); BAR;
    // ---- p7: q(1,1) ----
    if (more) {
      STG(Be, Bs + 2 * 8192, n0 + 0, ka + 3);
      asm volatile("s_waitcnt vmcnt(4)" ::: "memory");
      PUBFENCE;
    }
    BAR; MM16(3, bfB); BAR;
  }
#undef MM16
#undef RDB
#undef RDA
#undef PUBFENCE
#undef BAR

  // epilogue
#pragma unroll
  for (int q = 0; q < 4; ++q) {
    const int mh = q >> 1, nh = q & 1;
#pragma unroll
    for (int m = 0; m < 4; ++m) {
      const int rowb = m0 + mh * 128 + war + m * 16 + fq * 4;
      const int colb = n0 + nh * 128 + wbr + fr;
      if (FIRST) {
#pragma unroll
        for (int j = 0; j < 4; ++j) {
          size_t row = (size_t)z * 1024 + rowb + j;
#pragma unroll
          for (int n = 0; n < 2; ++n)
            Hout[row * (size_t)NDIM + colb + n * 16] = (_Float16)fmaxf(acc[q][m][n][j], 0.f);
        }
      } else {
        const int srow = z * CAP + rowb;
#pragma unroll
        for (int j = 0; j < 4; ++j) {
          int token = s2t[srow + j];
          if (token < 0) continue;
          float g = rgate[srow + j];
#pragma unroll
          for (int n = 0; n < 2; ++n) {
            if (SPLITK > 1)
              atomicAdd(&Y[(size_t)token * DDIM + colb + n * 16], acc[q][m][n][j] * g);
            else
              Y[(size_t)token * DDIM + colb + n * 16] = acc[q][m][n][j] * g;
          }
        }
      }
    }
  }
}

extern "C" void kernel_launch(void* const* d_in, const int* in_sizes, int n_in,
                              void* d_out, int out_size, void* d_ws, size_t ws_size,
                              hipStream_t stream) {
  const float* x  = (const float*)d_in[0];
  const float* wg = (const float*)d_in[1];
  const float* w1 = (const float*)d_in[2];
  const float* w2 = (const float*)d_in[3];
  float* y = (float*)d_out;

  char* ws = (char*)d_ws;
  int*   eidx  = (int*)(ws);                 // 32 KB
  float* gtok  = (float*)(ws + 32768);       // 32 KB
  int*   s2t   = (int*)(ws + 65536);         // 32 KB
  float* rgate = (float*)(ws + 98304);       // 32 KB
  int*   cnt   = (int*)(ws + 131072);        // 4 KB
  int*   off   = (int*)(ws + 135168);        // 4 KB
  _Float16* disp = (_Float16*)(ws + 147456); // 16 MB
  char* big = ws + 147456 + (size_t)NEXP * CAP * DDIM * 2;
  _Float16* hbuf = (_Float16*)big;                  // [E][C][H] fp16, 64 MB
  _Float16* wt   = (_Float16*)(big + 67108864);     // shared w1t then w2t, 64 MB

  moe_gating<<<S_TOK / 4, 256, 0, stream>>>(x, wg, eidx, gtok);
  scanA<<<128, 64, 0, stream>>>(eidx, cnt);
  scanB<<<1, 512, 0, stream>>>(cnt, off);
  (void)hipMemsetAsync(s2t, 0xFF, 32768, stream);
  (void)hipMemsetAsync(rgate, 0, 32768, stream);
  scanC<<<128, 64, 0, stream>>>(eidx, gtok, off, s2t, rgate);
  moe_dispatch<<<NEXP * CAP, 128, 0, stream>>>(x, s2t, disp);
  (void)hipMemsetAsync(d_out, 0, (size_t)out_size * sizeof(float), stream);

  // GEMM1: [C,1024] x [1024,4096] -> relu -> hbuf fp16.  8e x (4m x 16n) = 512 blocks
  transpose_cvt<<<dim3(HDIM / 64, DDIM / 64, NEXP), 256, 0, stream>>>(w1, wt, DDIM, HDIM);
  ffn_gemm_m<DDIM, HDIM, 1, true><<<512, 512, 0, stream>>>(
      disp, wt, hbuf, nullptr, nullptr, nullptr);

  // GEMM2: [C,4096] x [4096,1024] -> scatter-add to y.  8e x 16t x 2k = 256 blocks
  transpose_cvt<<<dim3(DDIM / 64, HDIM / 64, NEXP), 256, 0, stream>>>(w2, wt, HDIM, DDIM);
  ffn_gemm_m<HDIM, DDIM, 2, false><<<256, 512, 0, stream>>>(
      hbuf, wt, nullptr, y, s2t, rgate);
}